// Round 8
// baseline (265.919 us; speedup 1.0000x reference)
//
#include <hip/hip_runtime.h>
#include <hip/hip_bf16.h>

// GCN: 3x GCNConv (sym-norm, self-loops) + linear head.
// N=50000 nodes, E=800000 edges, F: 128 -> 128 -> 128 -> 64 -> 1.
// Round 22: (a) REVERT r21 16-deep agg (262.2 vs 258.9: ILP exhausted, reg
// pressure). Agg walk back to r20 8-deep everywhere. (b) FUSE agg+next-GEMM:
// block aggregates 64 nodes (16 subgroups x 4 passes, r20 walk verbatim) and
// writes split bf16 hi/lo DIRECTLY to the GEMM's LDS A-tile, then runs the
// MFMA GEMM from LDS (both col groups in-block; A-tile is expensive here so
// reuse is the point, unlike r16's pure-GEMM case). Eliminates the 100 MB
// bufHi/bufLo HBM round trip + 2 launches (10 -> 8). Distinct from r12's
// disproven per-edge phase fusion: gather loop unchanged, only its output
// destination moves from global to LDS.
// Kept: r20 subgroup-per-node 8-deep agg; r18 aligned ws; r17 ushort
// csr_src; r16 ticket scan.
// Disproven: panels (r10/r11), per-edge phase fusion (r12), coop build
// (r14), gemm col-group serialization for cheap A (r16), fat gemm1+build
// fusion (r19), 16-deep agg (r21).

#define N_NODES 50000
#define N_EDGES 800000
#define NBUCK 196
#define GB 196
#define EPB 4096

typedef __attribute__((ext_vector_type(8))) short short8;
typedef __attribute__((ext_vector_type(8))) unsigned short ushort8v;
typedef __attribute__((ext_vector_type(4))) float f32x4;

static __device__ __forceinline__ unsigned short f2bf(float f) {
    __hip_bfloat16 h = __float2bfloat16(f);
    return *reinterpret_cast<unsigned short*>(&h);
}
static __device__ __forceinline__ float bf2f(unsigned short u) {
    return __uint_as_float(((unsigned)u) << 16);
}

// ---------- CSR build (r18 form) ----------
__global__ __launch_bounds__(256) void hist_wprep_kernel(
    const int* __restrict__ dstv, int* __restrict__ H, int nE, int* __restrict__ ticket,
    const float* __restrict__ W1, const float* __restrict__ Wh, const float* __restrict__ W2,
    unsigned short* __restrict__ W1hi, unsigned short* __restrict__ W1lo,
    unsigned short* __restrict__ Whhi, unsigned short* __restrict__ Whlo,
    unsigned short* __restrict__ W2hi, unsigned short* __restrict__ W2lo) {
    int gt = blockIdx.x * 256 + threadIdx.x;
    if (gt == 0) *ticket = 0;
    if (gt < 40960) {
        const float* W; unsigned short *Hi, *Lo; int nout, lt;
        if (gt < 16384)      { W = W1; Hi = W1hi; Lo = W1lo; nout = 128; lt = gt; }
        else if (gt < 32768) { W = Wh; Hi = Whhi; Lo = Whlo; nout = 128; lt = gt - 16384; }
        else                 { W = W2; Hi = W2hi; Lo = W2lo; nout = 64;  lt = gt - 32768; }
        int col = lt % nout, k = lt / nout;
        float v = W[lt];
        unsigned short hi = f2bf(v);
        unsigned short lo = f2bf(v - bf2f(hi));
        Hi[(size_t)col * 128 + k] = hi;
        Lo[(size_t)col * 128 + k] = lo;
    }

    __shared__ int h[NBUCK];
    for (int i = threadIdx.x; i < NBUCK; i += 256) h[i] = 0;
    __syncthreads();
    int base = blockIdx.x * EPB;
#pragma unroll
    for (int i = 0; i < EPB / 256; ++i) {
        int e = base + i * 256 + threadIdx.x;
        if (e < nE) atomicAdd(&h[dstv[e] >> 8], 1);
    }
    __syncthreads();
    for (int i = threadIdx.x; i < NBUCK; i += 256)
        H[i * GB + blockIdx.x] = h[i];
}

__global__ __launch_bounds__(256) void scan_kernel(int* __restrict__ H,
                                                   int* __restrict__ bsum,
                                                   int* __restrict__ bstart,
                                                   int* __restrict__ rowoff_last,
                                                   int* __restrict__ ticket) {
    __shared__ int s[256];
    __shared__ int lastFlag;
    int t = threadIdx.x, k = blockIdx.x;
    int v = (t < GB) ? H[k * GB + t] : 0;
    s[t] = v;
    __syncthreads();
    for (int off = 1; off < 256; off <<= 1) {
        int u = (t >= off) ? s[t - off] : 0;
        __syncthreads();
        s[t] += u;
        __syncthreads();
    }
    if (t < GB) H[k * GB + t] = s[t] - v;
    if (t == 255) {
        bsum[k] = s[255];
        __threadfence();
        int tk = atomicAdd(ticket, 1);
        lastFlag = (tk == NBUCK - 1);
    }
    __syncthreads();
    if (!lastFlag) return;
    __threadfence();
    int v2 = (t < NBUCK) ? bsum[t] : 0;
    s[t] = v2;
    __syncthreads();
    for (int off = 1; off < 256; off <<= 1) {
        int u = (t >= off) ? s[t - off] : 0;
        __syncthreads();
        s[t] += u;
        __syncthreads();
    }
    if (t < NBUCK) bstart[t] = s[t] - v2;
    if (t == 0) { bstart[NBUCK] = N_EDGES; *rowoff_last = N_EDGES; }
}

__global__ __launch_bounds__(256) void partition_kernel(const int* __restrict__ srcv,
                                                        const int* __restrict__ dstv,
                                                        const int* __restrict__ H,
                                                        const int* __restrict__ bstart,
                                                        unsigned int* __restrict__ P, int nE) {
    __shared__ int cur[NBUCK];
    for (int i = threadIdx.x; i < NBUCK; i += 256)
        cur[i] = bstart[i] + H[i * GB + blockIdx.x];
    __syncthreads();
    int base = blockIdx.x * EPB;
#pragma unroll
    for (int i = 0; i < EPB / 256; ++i) {
        int e = base + i * 256 + threadIdx.x;
        if (e < nE) {
            int d = dstv[e];
            unsigned int pk = (unsigned int)srcv[e] | ((unsigned int)(d & 255) << 16);
            int pos = atomicAdd(&cur[d >> 8], 1);
            P[pos] = pk;
        }
    }
}

__global__ __launch_bounds__(256) void bucket_csr_kernel(const unsigned int* __restrict__ P,
                                                         const int* __restrict__ bstart,
                                                         int* __restrict__ rowoff,
                                                         float* __restrict__ dis,
                                                         unsigned short* __restrict__ csr_src, int n) {
    __shared__ int cnt[256];
    __shared__ int s[256];
    __shared__ int cur[256];
    int t = threadIdx.x, k = blockIdx.x;
    int ebeg = bstart[k], eend = bstart[k + 1];
    cnt[t] = 0;
    __syncthreads();
    for (int e = ebeg + t; e < eend; e += 256)
        atomicAdd(&cnt[(P[e] >> 16) & 255], 1);
    __syncthreads();
    int myc = cnt[t];
    s[t] = myc;
    __syncthreads();
    for (int off = 1; off < 256; off <<= 1) {
        int v = (t >= off) ? s[t - off] : 0;
        __syncthreads();
        s[t] += v;
        __syncthreads();
    }
    int excl = s[t] - myc;
    int node = (k << 8) + t;
    if (node < n) {
        rowoff[node] = ebeg + excl;
        dis[node] = rsqrtf((float)(myc + 1));
    }
    cur[t] = ebeg + excl;
    __syncthreads();
    for (int e = ebeg + t; e < eend; e += 256) {
        unsigned int p = P[e];
        int pos = atomicAdd(&cur[(p >> 16) & 255], 1);
        csr_src[pos] = (unsigned short)(p & 0xFFFFu);
    }
}

// ---------- GEMM compute phase from LDS tile (shared device code) ----------
template <int NOUT>
static __device__ __forceinline__ void gemm_from_lds(
    const unsigned short* sAhi, const unsigned short* sAlo, int tid, int Rbase,
    const unsigned short* __restrict__ Wthi, const unsigned short* __restrict__ Wtlo,
    const float* __restrict__ scale, unsigned short* __restrict__ C, int M) {
    constexpr int LDK = 136;
    int w = tid >> 6, lane = tid & 63;
    int quad = lane >> 4, m = lane & 15;
    int r0 = (w & 1) * 32, c0 = (w >> 1) * 32;

#pragma unroll
    for (int cb = 0; cb < NOUT / 64; ++cb) {
        int Cbase = cb * 64;
        short8 bh[4][2], bl[4][2];
#pragma unroll
        for (int ks = 0; ks < 4; ++ks)
#pragma unroll
            for (int g = 0; g < 2; ++g) {
                size_t off = (size_t)(Cbase + c0 + g * 16 + m) * 128 + ks * 32 + quad * 8;
                bh[ks][g] = *(const short8*)(Wthi + off);
                bl[ks][g] = *(const short8*)(Wtlo + off);
            }

        f32x4 z = {0.f, 0.f, 0.f, 0.f};
        f32x4 acc00 = z, acc01 = z, acc10 = z, acc11 = z;
#pragma unroll
        for (int ks = 0; ks < 4; ++ks) {
            int kof = ks * 32 + quad * 8;
            short8 ah0 = *(const short8*)(sAhi + (r0 + m) * LDK + kof);
            short8 ah1 = *(const short8*)(sAhi + (r0 + 16 + m) * LDK + kof);
            short8 al0 = *(const short8*)(sAlo + (r0 + m) * LDK + kof);
            short8 al1 = *(const short8*)(sAlo + (r0 + 16 + m) * LDK + kof);
            acc00 = __builtin_amdgcn_mfma_f32_16x16x32_bf16(ah0, bh[ks][0], acc00, 0, 0, 0);
            acc01 = __builtin_amdgcn_mfma_f32_16x16x32_bf16(ah0, bh[ks][1], acc01, 0, 0, 0);
            acc10 = __builtin_amdgcn_mfma_f32_16x16x32_bf16(ah1, bh[ks][0], acc10, 0, 0, 0);
            acc11 = __builtin_amdgcn_mfma_f32_16x16x32_bf16(ah1, bh[ks][1], acc11, 0, 0, 0);
            acc00 = __builtin_amdgcn_mfma_f32_16x16x32_bf16(ah0, bl[ks][0], acc00, 0, 0, 0);
            acc01 = __builtin_amdgcn_mfma_f32_16x16x32_bf16(ah0, bl[ks][1], acc01, 0, 0, 0);
            acc10 = __builtin_amdgcn_mfma_f32_16x16x32_bf16(ah1, bl[ks][0], acc10, 0, 0, 0);
            acc11 = __builtin_amdgcn_mfma_f32_16x16x32_bf16(ah1, bl[ks][1], acc11, 0, 0, 0);
            acc00 = __builtin_amdgcn_mfma_f32_16x16x32_bf16(al0, bh[ks][0], acc00, 0, 0, 0);
            acc01 = __builtin_amdgcn_mfma_f32_16x16x32_bf16(al0, bh[ks][1], acc01, 0, 0, 0);
            acc10 = __builtin_amdgcn_mfma_f32_16x16x32_bf16(al1, bh[ks][0], acc10, 0, 0, 0);
            acc11 = __builtin_amdgcn_mfma_f32_16x16x32_bf16(al1, bh[ks][1], acc11, 0, 0, 0);
        }

#pragma unroll
        for (int reg = 0; reg < 4; ++reg) {
            int row0g = Rbase + r0 + quad * 4 + reg;
            if (row0g < M) {
                float sc = scale[row0g];
                C[(size_t)row0g * NOUT + Cbase + c0 + m]      = f2bf(acc00[reg] * sc);
                C[(size_t)row0g * NOUT + Cbase + c0 + 16 + m] = f2bf(acc01[reg] * sc);
            }
            int row1g = row0g + 16;
            if (row1g < M) {
                float sc = scale[row1g];
                C[(size_t)row1g * NOUT + Cbase + c0 + m]      = f2bf(acc10[reg] * sc);
                C[(size_t)row1g * NOUT + Cbase + c0 + 16 + m] = f2bf(acc11[reg] * sc);
            }
        }
    }
}

// ---------- Layer-1 GEMM (fp32 x, split in staging; r20 form) ----------
__global__ __launch_bounds__(256) void gemm1_kernel(
    const float* __restrict__ A,
    const unsigned short* __restrict__ Wthi, const unsigned short* __restrict__ Wtlo,
    const float* __restrict__ scale, unsigned short* __restrict__ C, int M) {
    constexpr int LDK = 136;
    __shared__ unsigned short sAhi[64 * LDK];
    __shared__ unsigned short sAlo[64 * LDK];
    int tid = threadIdx.x;
    int Rbase = blockIdx.x * 64;

    for (int i = tid; i < 64 * 32; i += 256) {
        int r = i >> 5, c4 = i & 31;
        int row = Rbase + r;
        float4 v = make_float4(0.f, 0.f, 0.f, 0.f);
        if (row < M) v = ((const float4*)(A + (size_t)row * 128))[c4];
        ushort4 hi, lo;
        hi.x = f2bf(v.x); lo.x = f2bf(v.x - bf2f(hi.x));
        hi.y = f2bf(v.y); lo.y = f2bf(v.y - bf2f(hi.y));
        hi.z = f2bf(v.z); lo.z = f2bf(v.z - bf2f(hi.z));
        hi.w = f2bf(v.w); lo.w = f2bf(v.w - bf2f(hi.w));
        *(ushort4*)(sAhi + r * LDK + c4 * 4) = hi;
        *(ushort4*)(sAlo + r * LDK + c4 * 4) = lo;
    }
    __syncthreads();
    gemm_from_lds<128>(sAhi, sAlo, tid, Rbase, Wthi, Wtlo, scale, C, M);
}

// ---------- FUSED agg + GEMM ----------
// Block owns 64 nodes. Phase 1: 16 subgroups x 4 passes aggregate (r20
// 8-deep walk), relu(a*dis+b) split bf16 hi/lo -> LDS A-tile. Phase 2:
// MFMA GEMM from LDS (both col groups), C = bf16(result * dis[row]).
template <int NOUT>
__global__ __launch_bounds__(256) void agg_gemm_kernel(
    const int* __restrict__ rowoff, const unsigned short* __restrict__ csr_src,
    const float* __restrict__ dis, const unsigned short* __restrict__ tp,
    const float* __restrict__ bias,
    const unsigned short* __restrict__ Wthi, const unsigned short* __restrict__ Wtlo,
    unsigned short* __restrict__ C, int M) {
    constexpr int LDK = 136;
    __shared__ unsigned short sAhi[64 * LDK];
    __shared__ unsigned short sAlo[64 * LDK];
    int tid = threadIdx.x;
    int Rbase = blockIdx.x * 64;
    int s = tid >> 4, lc = tid & 15;

    float4 b0 = ((const float4*)bias)[lc * 2];
    float4 b1 = ((const float4*)bias)[lc * 2 + 1];

#pragma unroll
    for (int p = 0; p < 4; ++p) {
        int r = p * 16 + s;
        int node = Rbase + r;
        ushort8v hi = {0,0,0,0,0,0,0,0}, lo = {0,0,0,0,0,0,0,0};
        if (node < M) {
            float a[8] = {0.f,0.f,0.f,0.f,0.f,0.f,0.f,0.f};
#define ROW128(nd) (*(const ushort8v*)(tp + (size_t)(nd) * 128 + lc * 8))
#define ACC(u) { a[0] += bf2f(u[0]); a[1] += bf2f(u[1]); a[2] += bf2f(u[2]); a[3] += bf2f(u[3]); \
                 a[4] += bf2f(u[4]); a[5] += bf2f(u[5]); a[6] += bf2f(u[6]); a[7] += bf2f(u[7]); }
            { ushort8v u = ROW128(node); ACC(u); }  // self loop
            int i = rowoff[node], end = rowoff[node + 1];
            for (; i + 8 <= end; i += 8) {
                int p0 = csr_src[i],     p1 = csr_src[i + 1], p2 = csr_src[i + 2], p3 = csr_src[i + 3];
                int p4 = csr_src[i + 4], p5 = csr_src[i + 5], p6 = csr_src[i + 6], p7 = csr_src[i + 7];
                ushort8v u0 = ROW128(p0), u1 = ROW128(p1), u2 = ROW128(p2), u3 = ROW128(p3);
                ushort8v u4 = ROW128(p4), u5 = ROW128(p5), u6 = ROW128(p6), u7 = ROW128(p7);
                ACC(u0); ACC(u1); ACC(u2); ACC(u3); ACC(u4); ACC(u5); ACC(u6); ACC(u7);
            }
            if (i + 4 <= end) {
                int p0 = csr_src[i], p1 = csr_src[i + 1], p2 = csr_src[i + 2], p3 = csr_src[i + 3];
                ushort8v u0 = ROW128(p0), u1 = ROW128(p1), u2 = ROW128(p2), u3 = ROW128(p3);
                ACC(u0); ACC(u1); ACC(u2); ACC(u3);
                i += 4;
            }
            if (i + 2 <= end) {
                int p0 = csr_src[i], p1 = csr_src[i + 1];
                ushort8v u0 = ROW128(p0), u1 = ROW128(p1);
                ACC(u0); ACC(u1);
                i += 2;
            }
            if (i < end) { ushort8v u = ROW128(csr_src[i]); ACC(u); }
#undef ROW128
#undef ACC
            float dd = dis[node];
            float rr[8];
            rr[0] = fmaxf(a[0] * dd + b0.x, 0.f);
            rr[1] = fmaxf(a[1] * dd + b0.y, 0.f);
            rr[2] = fmaxf(a[2] * dd + b0.z, 0.f);
            rr[3] = fmaxf(a[3] * dd + b0.w, 0.f);
            rr[4] = fmaxf(a[4] * dd + b1.x, 0.f);
            rr[5] = fmaxf(a[5] * dd + b1.y, 0.f);
            rr[6] = fmaxf(a[6] * dd + b1.z, 0.f);
            rr[7] = fmaxf(a[7] * dd + b1.w, 0.f);
#pragma unroll
            for (int j = 0; j < 8; ++j) {
                hi[j] = f2bf(rr[j]);
                lo[j] = f2bf(rr[j] - bf2f(hi[j]));
            }
        }
        *(ushort8v*)(sAhi + r * LDK + lc * 8) = hi;
        *(ushort8v*)(sAlo + r * LDK + lc * 8) = lo;
    }
    __syncthreads();

    gemm_from_lds<NOUT>(sAhi, sAlo, tid, Rbase, Wthi, Wtlo, dis, C, M);
}

// ---------- agg64 + head (r20 form, 8-deep) ----------
__global__ __launch_bounds__(256) void aggregate64_head_kernel(
    const int* __restrict__ rowoff, const unsigned short* __restrict__ csr_src,
    const float* __restrict__ dis, const unsigned short* __restrict__ tp,
    const float* __restrict__ bias, const float* __restrict__ Wout,
    const float* __restrict__ bout, float* __restrict__ hout,
    float* __restrict__ out, int n) {
    int gt = blockIdx.x * 256 + threadIdx.x;
    int node = gt >> 4;
    if (node >= n) return;
    int lc = gt & 15;

    float a[4] = {0.f,0.f,0.f,0.f};

#define ROW64(nd) (*((const ushort4*)(tp + (size_t)(nd) * 64 + lc * 4)))
#define ACC2(u) { a[0] += bf2f(u.x); a[1] += bf2f(u.y); a[2] += bf2f(u.z); a[3] += bf2f(u.w); }

    { ushort4 u = ROW64(node); ACC2(u); }  // self loop

    int i = rowoff[node], end = rowoff[node + 1];
    for (; i + 8 <= end; i += 8) {
        int p0 = csr_src[i],     p1 = csr_src[i + 1], p2 = csr_src[i + 2], p3 = csr_src[i + 3];
        int p4 = csr_src[i + 4], p5 = csr_src[i + 5], p6 = csr_src[i + 6], p7 = csr_src[i + 7];
        ushort4 u0 = ROW64(p0), u1 = ROW64(p1), u2 = ROW64(p2), u3 = ROW64(p3);
        ushort4 u4 = ROW64(p4), u5 = ROW64(p5), u6 = ROW64(p6), u7 = ROW64(p7);
        ACC2(u0); ACC2(u1); ACC2(u2); ACC2(u3); ACC2(u4); ACC2(u5); ACC2(u6); ACC2(u7);
    }
    if (i + 4 <= end) {
        int p0 = csr_src[i], p1 = csr_src[i + 1], p2 = csr_src[i + 2], p3 = csr_src[i + 3];
        ushort4 u0 = ROW64(p0), u1 = ROW64(p1), u2 = ROW64(p2), u3 = ROW64(p3);
        ACC2(u0); ACC2(u1); ACC2(u2); ACC2(u3);
        i += 4;
    }
    if (i + 2 <= end) {
        int p0 = csr_src[i], p1 = csr_src[i + 1];
        ushort4 u0 = ROW64(p0), u1 = ROW64(p1);
        ACC2(u0); ACC2(u1);
        i += 2;
    }
    if (i < end) { ushort4 u = ROW64(csr_src[i]); ACC2(u); }
#undef ROW64
#undef ACC2

    float dd = dis[node];
    float4 b = ((const float4*)bias)[lc];
    float4 hv;
    hv.x = a[0] * dd + b.x;
    hv.y = a[1] * dd + b.y;
    hv.z = a[2] * dd + b.z;
    hv.w = a[3] * dd + b.w;
    ((float4*)(hout + (size_t)node * 64))[lc] = hv;

    float4 wv = ((const float4*)Wout)[lc];
    float p = hv.x * wv.x + hv.y * wv.y + hv.z * wv.z + hv.w * wv.w;
#pragma unroll
    for (int off = 8; off > 0; off >>= 1) p += __shfl_xor(p, off);  // within subgroup
    if (lc == 0) out[node] = p + bout[0];
}

extern "C" void kernel_launch(void* const* d_in, const int* in_sizes, int n_in,
                              void* d_out, int out_size, void* d_ws, size_t ws_size,
                              hipStream_t stream) {
    const float* x    = (const float*)d_in[0];
    const int*   ei   = (const int*)d_in[1];
    const float* W1   = (const float*)d_in[2];
    const float* b1   = (const float*)d_in[3];
    const float* Wh   = (const float*)d_in[4];
    const float* bh   = (const float*)d_in[5];
    const float* W2   = (const float*)d_in[6];
    const float* b2   = (const float*)d_in[7];
    const float* Wout = (const float*)d_in[8];
    const float* bout = (const float*)d_in[9];

    const int N = N_NODES;
    const int E = N_EDGES;
    const int* srcv = ei;
    const int* dstv = ei + E;

    float* out  = (float*)d_out;
    float* hout = (float*)d_out + N;

    char* ws = (char*)d_ws;
    auto alloc = [&](size_t bytes) -> char* {
        char* p = ws;
        ws += (bytes + 255) & ~(size_t)255;
        return p;
    };
    int*   H       = (int*)alloc(sizeof(int) * NBUCK * GB);
    int*   bsum    = (int*)alloc(sizeof(int) * NBUCK);
    int*   bstart  = (int*)alloc(sizeof(int) * (NBUCK + 1));
    int*   ticket  = (int*)alloc(sizeof(int) * 4);
    int*   rowoff  = (int*)alloc(sizeof(int) * (N + 1));
    unsigned int* P = (unsigned int*)alloc(sizeof(unsigned int) * E);
    unsigned short* csr_src = (unsigned short*)alloc(sizeof(unsigned short) * (E + 8));
    float* dis     = (float*)alloc(sizeof(float) * N);
    unsigned short* W1thi = (unsigned short*)alloc(sizeof(unsigned short) * 128 * 128);
    unsigned short* W1tlo = (unsigned short*)alloc(sizeof(unsigned short) * 128 * 128);
    unsigned short* Whthi = (unsigned short*)alloc(sizeof(unsigned short) * 128 * 128);
    unsigned short* Whtlo = (unsigned short*)alloc(sizeof(unsigned short) * 128 * 128);
    unsigned short* W2thi = (unsigned short*)alloc(sizeof(unsigned short) * 64 * 128);
    unsigned short* W2tlo = (unsigned short*)alloc(sizeof(unsigned short) * 64 * 128);
    unsigned short* bufA  = (unsigned short*)alloc(sizeof(unsigned short) * (size_t)N * 128);
    unsigned short* bufB  = (unsigned short*)alloc(sizeof(unsigned short) * (size_t)N * 128);

    // --- CSR build ---
    hist_wprep_kernel<<<GB, 256, 0, stream>>>(dstv, H, E, ticket,
                                              W1, Wh, W2, W1thi, W1tlo, Whthi, Whtlo, W2thi, W2tlo);
    scan_kernel<<<NBUCK, 256, 0, stream>>>(H, bsum, bstart, rowoff + N, ticket);
    partition_kernel<<<GB, 256, 0, stream>>>(srcv, dstv, H, bstart, P, E);
    bucket_csr_kernel<<<NBUCK, 256, 0, stream>>>(P, bstart, rowoff, dis, csr_src, N);

    const int aggBlocks  = (N * 16 + 255) / 256;  // 16 lanes per node
    const int tileBlocks = (N + 63) / 64;         // 782

    // --- layer 1: h1-rows = bf16((x@W1) * dis)  (scaled bf16 plane) ---
    gemm1_kernel<<<tileBlocks, 256, 0, stream>>>(x, W1thi, W1tlo, dis, bufA, N);

    // --- fused: h1 = relu(agg(bufA)+b1) -> LDS -> @Wh * dis -> bufB ---
    agg_gemm_kernel<128><<<tileBlocks, 256, 0, stream>>>(
        rowoff, csr_src, dis, bufA, b1, Whthi, Whtlo, bufB, N);

    // --- fused: h2 = relu(agg(bufB)+bh) -> LDS -> @W2 * dis -> bufA(64) ---
    agg_gemm_kernel<64><<<tileBlocks, 256, 0, stream>>>(
        rowoff, csr_src, dis, bufB, bh, W2thi, W2tlo, bufA, N);

    // --- layer 3 agg + head ---
    aggregate64_head_kernel<<<aggBlocks, 256, 0, stream>>>(
        rowoff, csr_src, dis, bufA, b2, Wout, bout, hout, out, N);
}

// Round 9
// 257.216 us; speedup vs baseline: 1.0338x; 1.0338x over previous
//
#include <hip/hip_runtime.h>
#include <hip/hip_bf16.h>

// GCN: 3x GCNConv (sym-norm, self-loops) + linear head.
// N=50000 nodes, E=800000 edges, F: 128 -> 128 -> 128 -> 64 -> 1.
// Round 23: REVERT r22 agg+gemm fusion (measured 265.9 vs r20 258.9;
// counters: occupancy 32->20.7%, HBM 2.3->1.39 TB/s — gather concurrency
// collapsed under the GEMM's 34KB LDS cap; fusion saves 16us of HBM but
// costs 23us of latency hiding). Back to r20 exactly, plus: build widened
// GB 196->256 (EPB 3328) for full CU coverage; scan per-bucket width = 256
// = blockDim (guard-free).
// Established: agg is bounded by random-256B-granule effective throughput
// (~4.6 TB/s logical; r21 deeper ILP null, r22 fusion negative) — structural
// floor for this access pattern.
// Disproven: panels (r10/r11), per-edge phase fusion (r12), coop build
// (r14), gemm col-group serialization for cheap A (r16), fat gemm1+build
// fusion (r19), 16-deep agg (r21), agg+gemm LDS fusion (r22).

#define N_NODES 50000
#define N_EDGES 800000
#define NBUCK 196          // ceil(N/256) coarse buckets (dst>>8)
#define GB 256             // edge-chunk blocks (= scan width, guard-free)
#define EPB 3328           // 13*256; GB*EPB = 851968 >= E

typedef __attribute__((ext_vector_type(8))) short short8;
typedef __attribute__((ext_vector_type(8))) unsigned short ushort8v;
typedef __attribute__((ext_vector_type(4))) float f32x4;

static __device__ __forceinline__ unsigned short f2bf(float f) {
    __hip_bfloat16 h = __float2bfloat16(f);
    return *reinterpret_cast<unsigned short*>(&h);
}
static __device__ __forceinline__ float bf2f(unsigned short u) {
    return __uint_as_float(((unsigned)u) << 16);
}

// ---------- CSR build ----------
__global__ __launch_bounds__(256) void hist_wprep_kernel(
    const int* __restrict__ dstv, int* __restrict__ H, int nE, int* __restrict__ ticket,
    const float* __restrict__ W1, const float* __restrict__ Wh, const float* __restrict__ W2,
    unsigned short* __restrict__ W1hi, unsigned short* __restrict__ W1lo,
    unsigned short* __restrict__ Whhi, unsigned short* __restrict__ Whlo,
    unsigned short* __restrict__ W2hi, unsigned short* __restrict__ W2lo) {
    int gt = blockIdx.x * 256 + threadIdx.x;
    if (gt == 0) *ticket = 0;
    if (gt < 40960) {
        const float* W; unsigned short *Hi, *Lo; int nout, lt;
        if (gt < 16384)      { W = W1; Hi = W1hi; Lo = W1lo; nout = 128; lt = gt; }
        else if (gt < 32768) { W = Wh; Hi = Whhi; Lo = Whlo; nout = 128; lt = gt - 16384; }
        else                 { W = W2; Hi = W2hi; Lo = W2lo; nout = 64;  lt = gt - 32768; }
        int col = lt % nout, k = lt / nout;
        float v = W[lt];
        unsigned short hi = f2bf(v);
        unsigned short lo = f2bf(v - bf2f(hi));
        Hi[(size_t)col * 128 + k] = hi;
        Lo[(size_t)col * 128 + k] = lo;
    }

    __shared__ int h[NBUCK];
    for (int i = threadIdx.x; i < NBUCK; i += 256) h[i] = 0;
    __syncthreads();
    int base = blockIdx.x * EPB;
#pragma unroll
    for (int i = 0; i < EPB / 256; ++i) {
        int e = base + i * 256 + threadIdx.x;
        if (e < nE) atomicAdd(&h[dstv[e] >> 8], 1);
    }
    __syncthreads();
    for (int i = threadIdx.x; i < NBUCK; i += 256)
        H[i * GB + blockIdx.x] = h[i];
}

__global__ __launch_bounds__(256) void scan_kernel(int* __restrict__ H,
                                                   int* __restrict__ bsum,
                                                   int* __restrict__ bstart,
                                                   int* __restrict__ rowoff_last,
                                                   int* __restrict__ ticket) {
    __shared__ int s[256];
    __shared__ int lastFlag;
    int t = threadIdx.x, k = blockIdx.x;
    int v = H[k * GB + t];          // GB == 256 == blockDim: guard-free
    s[t] = v;
    __syncthreads();
    for (int off = 1; off < 256; off <<= 1) {
        int u = (t >= off) ? s[t - off] : 0;
        __syncthreads();
        s[t] += u;
        __syncthreads();
    }
    H[k * GB + t] = s[t] - v;       // local exclusive
    if (t == 255) {
        bsum[k] = s[255];
        __threadfence();
        int tk = atomicAdd(ticket, 1);
        lastFlag = (tk == NBUCK - 1);
    }
    __syncthreads();
    if (!lastFlag) return;
    __threadfence();
    int v2 = (t < NBUCK) ? bsum[t] : 0;
    s[t] = v2;
    __syncthreads();
    for (int off = 1; off < 256; off <<= 1) {
        int u = (t >= off) ? s[t - off] : 0;
        __syncthreads();
        s[t] += u;
        __syncthreads();
    }
    if (t < NBUCK) bstart[t] = s[t] - v2;
    if (t == 0) { bstart[NBUCK] = N_EDGES; *rowoff_last = N_EDGES; }
}

__global__ __launch_bounds__(256) void partition_kernel(const int* __restrict__ srcv,
                                                        const int* __restrict__ dstv,
                                                        const int* __restrict__ H,
                                                        const int* __restrict__ bstart,
                                                        unsigned int* __restrict__ P, int nE) {
    __shared__ int cur[NBUCK];
    for (int i = threadIdx.x; i < NBUCK; i += 256)
        cur[i] = bstart[i] + H[i * GB + blockIdx.x];
    __syncthreads();
    int base = blockIdx.x * EPB;
#pragma unroll
    for (int i = 0; i < EPB / 256; ++i) {
        int e = base + i * 256 + threadIdx.x;
        if (e < nE) {
            int d = dstv[e];
            unsigned int pk = (unsigned int)srcv[e] | ((unsigned int)(d & 255) << 16);
            int pos = atomicAdd(&cur[d >> 8], 1);
            P[pos] = pk;
        }
    }
}

__global__ __launch_bounds__(256) void bucket_csr_kernel(const unsigned int* __restrict__ P,
                                                         const int* __restrict__ bstart,
                                                         int* __restrict__ rowoff,
                                                         float* __restrict__ dis,
                                                         unsigned short* __restrict__ csr_src, int n) {
    __shared__ int cnt[256];
    __shared__ int s[256];
    __shared__ int cur[256];
    int t = threadIdx.x, k = blockIdx.x;
    int ebeg = bstart[k], eend = bstart[k + 1];
    cnt[t] = 0;
    __syncthreads();
    for (int e = ebeg + t; e < eend; e += 256)
        atomicAdd(&cnt[(P[e] >> 16) & 255], 1);
    __syncthreads();
    int myc = cnt[t];
    s[t] = myc;
    __syncthreads();
    for (int off = 1; off < 256; off <<= 1) {
        int v = (t >= off) ? s[t - off] : 0;
        __syncthreads();
        s[t] += v;
        __syncthreads();
    }
    int excl = s[t] - myc;
    int node = (k << 8) + t;
    if (node < n) {
        rowoff[node] = ebeg + excl;
        dis[node] = rsqrtf((float)(myc + 1));
    }
    cur[t] = ebeg + excl;
    __syncthreads();
    for (int e = ebeg + t; e < eend; e += 256) {
        unsigned int p = P[e];
        int pos = atomicAdd(&cur[(p >> 16) & 255], 1);
        csr_src[pos] = (unsigned short)(p & 0xFFFFu);
    }
}

// ---------- MFMA GEMM: C[r] = bf16((A[r] @ W) * scale[r]) ----------
template <int NOUT, bool SPLITA>
__global__ __launch_bounds__(256) void gemm_mfma_kernel(
    const float* __restrict__ A,
    const unsigned short* __restrict__ Ahi, const unsigned short* __restrict__ Alo,
    const unsigned short* __restrict__ Wthi, const unsigned short* __restrict__ Wtlo,
    const float* __restrict__ scale, unsigned short* __restrict__ C, int M) {
    constexpr int LDK = 136;
    __shared__ unsigned short sAhi[64 * LDK];
    __shared__ unsigned short sAlo[64 * LDK];

    int tid = threadIdx.x;
    int w = tid >> 6, lane = tid & 63;
    int quad = lane >> 4, m = lane & 15;
    int Rbase = blockIdx.x * 64, Cbase = blockIdx.y * 64;
    int r0 = (w & 1) * 32, c0 = (w >> 1) * 32;

    short8 bh[4][2], bl[4][2];
#pragma unroll
    for (int ks = 0; ks < 4; ++ks)
#pragma unroll
        for (int g = 0; g < 2; ++g) {
            size_t off = (size_t)(Cbase + c0 + g * 16 + m) * 128 + ks * 32 + quad * 8;
            bh[ks][g] = *(const short8*)(Wthi + off);
            bl[ks][g] = *(const short8*)(Wtlo + off);
        }

    if constexpr (SPLITA) {
        for (int i = tid; i < 64 * 16; i += 256) {
            int r = i >> 4, c8 = i & 15;
            int row = Rbase + r;
            short8 hv = {0,0,0,0,0,0,0,0}, lv = {0,0,0,0,0,0,0,0};
            if (row < M) {
                hv = *(const short8*)(Ahi + (size_t)row * 128 + c8 * 8);
                lv = *(const short8*)(Alo + (size_t)row * 128 + c8 * 8);
            }
            *(short8*)(sAhi + r * LDK + c8 * 8) = hv;
            *(short8*)(sAlo + r * LDK + c8 * 8) = lv;
        }
    } else {
        for (int i = tid; i < 64 * 32; i += 256) {
            int r = i >> 5, c4 = i & 31;
            int row = Rbase + r;
            float4 v = make_float4(0.f, 0.f, 0.f, 0.f);
            if (row < M) v = ((const float4*)(A + (size_t)row * 128))[c4];
            ushort4 hi, lo;
            hi.x = f2bf(v.x); lo.x = f2bf(v.x - bf2f(hi.x));
            hi.y = f2bf(v.y); lo.y = f2bf(v.y - bf2f(hi.y));
            hi.z = f2bf(v.z); lo.z = f2bf(v.z - bf2f(hi.z));
            hi.w = f2bf(v.w); lo.w = f2bf(v.w - bf2f(hi.w));
            *(ushort4*)(sAhi + r * LDK + c4 * 4) = hi;
            *(ushort4*)(sAlo + r * LDK + c4 * 4) = lo;
        }
    }
    __syncthreads();

    f32x4 z = {0.f, 0.f, 0.f, 0.f};
    f32x4 acc00 = z, acc01 = z, acc10 = z, acc11 = z;

#pragma unroll
    for (int ks = 0; ks < 4; ++ks) {
        int kof = ks * 32 + quad * 8;
        short8 ah0 = *(const short8*)(sAhi + (r0 + m) * LDK + kof);
        short8 ah1 = *(const short8*)(sAhi + (r0 + 16 + m) * LDK + kof);
        short8 al0 = *(const short8*)(sAlo + (r0 + m) * LDK + kof);
        short8 al1 = *(const short8*)(sAlo + (r0 + 16 + m) * LDK + kof);
        acc00 = __builtin_amdgcn_mfma_f32_16x16x32_bf16(ah0, bh[ks][0], acc00, 0, 0, 0);
        acc01 = __builtin_amdgcn_mfma_f32_16x16x32_bf16(ah0, bh[ks][1], acc01, 0, 0, 0);
        acc10 = __builtin_amdgcn_mfma_f32_16x16x32_bf16(ah1, bh[ks][0], acc10, 0, 0, 0);
        acc11 = __builtin_amdgcn_mfma_f32_16x16x32_bf16(ah1, bh[ks][1], acc11, 0, 0, 0);
        acc00 = __builtin_amdgcn_mfma_f32_16x16x32_bf16(ah0, bl[ks][0], acc00, 0, 0, 0);
        acc01 = __builtin_amdgcn_mfma_f32_16x16x32_bf16(ah0, bl[ks][1], acc01, 0, 0, 0);
        acc10 = __builtin_amdgcn_mfma_f32_16x16x32_bf16(ah1, bl[ks][0], acc10, 0, 0, 0);
        acc11 = __builtin_amdgcn_mfma_f32_16x16x32_bf16(ah1, bl[ks][1], acc11, 0, 0, 0);
        acc00 = __builtin_amdgcn_mfma_f32_16x16x32_bf16(al0, bh[ks][0], acc00, 0, 0, 0);
        acc01 = __builtin_amdgcn_mfma_f32_16x16x32_bf16(al0, bh[ks][1], acc01, 0, 0, 0);
        acc10 = __builtin_amdgcn_mfma_f32_16x16x32_bf16(al1, bh[ks][0], acc10, 0, 0, 0);
        acc11 = __builtin_amdgcn_mfma_f32_16x16x32_bf16(al1, bh[ks][1], acc11, 0, 0, 0);
    }

#pragma unroll
    for (int reg = 0; reg < 4; ++reg) {
        int row0g = Rbase + r0 + quad * 4 + reg;
        if (row0g < M) {
            float sc = scale[row0g];
            C[(size_t)row0g * NOUT + Cbase + c0 + m]      = f2bf(acc00[reg] * sc);
            C[(size_t)row0g * NOUT + Cbase + c0 + 16 + m] = f2bf(acc01[reg] * sc);
        }
        int row1g = row0g + 16;
        if (row1g < M) {
            float sc = scale[row1g];
            C[(size_t)row1g * NOUT + Cbase + c0 + m]      = f2bf(acc10[reg] * sc);
            C[(size_t)row1g * NOUT + Cbase + c0 + 16 + m] = f2bf(acc11[reg] * sc);
        }
    }
}

// ---------- Aggregation: 16-lane subgroup per node, 8-deep ILP (r20) -------
__global__ __launch_bounds__(256) void aggregate128_kernel(
    const int* __restrict__ rowoff, const unsigned short* __restrict__ csr_src,
    const float* __restrict__ dis, const unsigned short* __restrict__ tp,
    const float* __restrict__ bias,
    unsigned short* __restrict__ outHi, unsigned short* __restrict__ outLo, int n) {
    int gt = blockIdx.x * 256 + threadIdx.x;
    int node = gt >> 4;
    if (node >= n) return;
    int lc = gt & 15;

    float a[8] = {0.f,0.f,0.f,0.f,0.f,0.f,0.f,0.f};

#define ROW128(nd) (*(const ushort8v*)(tp + (size_t)(nd) * 128 + lc * 8))
#define ACC(u) { a[0] += bf2f(u[0]); a[1] += bf2f(u[1]); a[2] += bf2f(u[2]); a[3] += bf2f(u[3]); \
                 a[4] += bf2f(u[4]); a[5] += bf2f(u[5]); a[6] += bf2f(u[6]); a[7] += bf2f(u[7]); }

    { ushort8v u = ROW128(node); ACC(u); }  // self loop

    int i = rowoff[node], end = rowoff[node + 1];
    for (; i + 8 <= end; i += 8) {
        int p0 = csr_src[i],     p1 = csr_src[i + 1], p2 = csr_src[i + 2], p3 = csr_src[i + 3];
        int p4 = csr_src[i + 4], p5 = csr_src[i + 5], p6 = csr_src[i + 6], p7 = csr_src[i + 7];
        ushort8v u0 = ROW128(p0), u1 = ROW128(p1), u2 = ROW128(p2), u3 = ROW128(p3);
        ushort8v u4 = ROW128(p4), u5 = ROW128(p5), u6 = ROW128(p6), u7 = ROW128(p7);
        ACC(u0); ACC(u1); ACC(u2); ACC(u3); ACC(u4); ACC(u5); ACC(u6); ACC(u7);
    }
    if (i + 4 <= end) {
        int p0 = csr_src[i], p1 = csr_src[i + 1], p2 = csr_src[i + 2], p3 = csr_src[i + 3];
        ushort8v u0 = ROW128(p0), u1 = ROW128(p1), u2 = ROW128(p2), u3 = ROW128(p3);
        ACC(u0); ACC(u1); ACC(u2); ACC(u3);
        i += 4;
    }
    if (i + 2 <= end) {
        int p0 = csr_src[i], p1 = csr_src[i + 1];
        ushort8v u0 = ROW128(p0), u1 = ROW128(p1);
        ACC(u0); ACC(u1);
        i += 2;
    }
    if (i < end) { ushort8v u = ROW128(csr_src[i]); ACC(u); }
#undef ROW128
#undef ACC

    float dd = dis[node];
    float4 b0 = ((const float4*)bias)[lc * 2];
    float4 b1 = ((const float4*)bias)[lc * 2 + 1];
    float r[8];
    r[0] = fmaxf(a[0] * dd + b0.x, 0.f);
    r[1] = fmaxf(a[1] * dd + b0.y, 0.f);
    r[2] = fmaxf(a[2] * dd + b0.z, 0.f);
    r[3] = fmaxf(a[3] * dd + b0.w, 0.f);
    r[4] = fmaxf(a[4] * dd + b1.x, 0.f);
    r[5] = fmaxf(a[5] * dd + b1.y, 0.f);
    r[6] = fmaxf(a[6] * dd + b1.z, 0.f);
    r[7] = fmaxf(a[7] * dd + b1.w, 0.f);
    ushort8v hi, lo;
#pragma unroll
    for (int j = 0; j < 8; ++j) {
        hi[j] = f2bf(r[j]);
        lo[j] = f2bf(r[j] - bf2f(hi[j]));
    }
    *(ushort8v*)(outHi + (size_t)node * 128 + lc * 8) = hi;
    *(ushort8v*)(outLo + (size_t)node * 128 + lc * 8) = lo;
}

// F=64 + fused head: 16-lane subgroup per node, ushort4 rows, 8-deep (r20).
__global__ __launch_bounds__(256) void aggregate64_head_kernel(
    const int* __restrict__ rowoff, const unsigned short* __restrict__ csr_src,
    const float* __restrict__ dis, const unsigned short* __restrict__ tp,
    const float* __restrict__ bias, const float* __restrict__ Wout,
    const float* __restrict__ bout, float* __restrict__ hout,
    float* __restrict__ out, int n) {
    int gt = blockIdx.x * 256 + threadIdx.x;
    int node = gt >> 4;
    if (node >= n) return;
    int lc = gt & 15;

    float a[4] = {0.f,0.f,0.f,0.f};

#define ROW64(nd) (*((const ushort4*)(tp + (size_t)(nd) * 64 + lc * 4)))
#define ACC2(u) { a[0] += bf2f(u.x); a[1] += bf2f(u.y); a[2] += bf2f(u.z); a[3] += bf2f(u.w); }

    { ushort4 u = ROW64(node); ACC2(u); }  // self loop

    int i = rowoff[node], end = rowoff[node + 1];
    for (; i + 8 <= end; i += 8) {
        int p0 = csr_src[i],     p1 = csr_src[i + 1], p2 = csr_src[i + 2], p3 = csr_src[i + 3];
        int p4 = csr_src[i + 4], p5 = csr_src[i + 5], p6 = csr_src[i + 6], p7 = csr_src[i + 7];
        ushort4 u0 = ROW64(p0), u1 = ROW64(p1), u2 = ROW64(p2), u3 = ROW64(p3);
        ushort4 u4 = ROW64(p4), u5 = ROW64(p5), u6 = ROW64(p6), u7 = ROW64(p7);
        ACC2(u0); ACC2(u1); ACC2(u2); ACC2(u3); ACC2(u4); ACC2(u5); ACC2(u6); ACC2(u7);
    }
    if (i + 4 <= end) {
        int p0 = csr_src[i], p1 = csr_src[i + 1], p2 = csr_src[i + 2], p3 = csr_src[i + 3];
        ushort4 u0 = ROW64(p0), u1 = ROW64(p1), u2 = ROW64(p2), u3 = ROW64(p3);
        ACC2(u0); ACC2(u1); ACC2(u2); ACC2(u3);
        i += 4;
    }
    if (i + 2 <= end) {
        int p0 = csr_src[i], p1 = csr_src[i + 1];
        ushort4 u0 = ROW64(p0), u1 = ROW64(p1);
        ACC2(u0); ACC2(u1);
        i += 2;
    }
    if (i < end) { ushort4 u = ROW64(csr_src[i]); ACC2(u); }
#undef ROW64
#undef ACC2

    float dd = dis[node];
    float4 b = ((const float4*)bias)[lc];
    float4 hv;
    hv.x = a[0] * dd + b.x;
    hv.y = a[1] * dd + b.y;
    hv.z = a[2] * dd + b.z;
    hv.w = a[3] * dd + b.w;
    ((float4*)(hout + (size_t)node * 64))[lc] = hv;

    float4 wv = ((const float4*)Wout)[lc];
    float p = hv.x * wv.x + hv.y * wv.y + hv.z * wv.z + hv.w * wv.w;
#pragma unroll
    for (int off = 8; off > 0; off >>= 1) p += __shfl_xor(p, off);  // within subgroup
    if (lc == 0) out[node] = p + bout[0];
}

extern "C" void kernel_launch(void* const* d_in, const int* in_sizes, int n_in,
                              void* d_out, int out_size, void* d_ws, size_t ws_size,
                              hipStream_t stream) {
    const float* x    = (const float*)d_in[0];
    const int*   ei   = (const int*)d_in[1];
    const float* W1   = (const float*)d_in[2];
    const float* b1   = (const float*)d_in[3];
    const float* Wh   = (const float*)d_in[4];
    const float* bh   = (const float*)d_in[5];
    const float* W2   = (const float*)d_in[6];
    const float* b2   = (const float*)d_in[7];
    const float* Wout = (const float*)d_in[8];
    const float* bout = (const float*)d_in[9];

    const int N = N_NODES;
    const int E = N_EDGES;
    const int* srcv = ei;
    const int* dstv = ei + E;

    float* out  = (float*)d_out;
    float* hout = (float*)d_out + N;

    char* ws = (char*)d_ws;
    auto alloc = [&](size_t bytes) -> char* {
        char* p = ws;
        ws += (bytes + 255) & ~(size_t)255;
        return p;
    };
    int*   H       = (int*)alloc(sizeof(int) * NBUCK * GB);
    int*   bsum    = (int*)alloc(sizeof(int) * NBUCK);
    int*   bstart  = (int*)alloc(sizeof(int) * (NBUCK + 1));
    int*   ticket  = (int*)alloc(sizeof(int) * 4);
    int*   rowoff  = (int*)alloc(sizeof(int) * (N + 1));
    unsigned int* P = (unsigned int*)alloc(sizeof(unsigned int) * E);
    unsigned short* csr_src = (unsigned short*)alloc(sizeof(unsigned short) * (E + 8));
    float* dis     = (float*)alloc(sizeof(float) * N);
    unsigned short* W1thi = (unsigned short*)alloc(sizeof(unsigned short) * 128 * 128);
    unsigned short* W1tlo = (unsigned short*)alloc(sizeof(unsigned short) * 128 * 128);
    unsigned short* Whthi = (unsigned short*)alloc(sizeof(unsigned short) * 128 * 128);
    unsigned short* Whtlo = (unsigned short*)alloc(sizeof(unsigned short) * 128 * 128);
    unsigned short* W2thi = (unsigned short*)alloc(sizeof(unsigned short) * 64 * 128);
    unsigned short* W2tlo = (unsigned short*)alloc(sizeof(unsigned short) * 64 * 128);
    unsigned short* bufT  = (unsigned short*)alloc(sizeof(unsigned short) * (size_t)N * 128);
    unsigned short* bufHi = (unsigned short*)alloc(sizeof(unsigned short) * (size_t)N * 128);
    unsigned short* bufLo = (unsigned short*)alloc(sizeof(unsigned short) * (size_t)N * 128);

    // --- CSR build ---
    hist_wprep_kernel<<<GB, 256, 0, stream>>>(dstv, H, E, ticket,
                                              W1, Wh, W2, W1thi, W1tlo, Whthi, Whtlo, W2thi, W2tlo);
    scan_kernel<<<NBUCK, 256, 0, stream>>>(H, bsum, bstart, rowoff + N, ticket);
    partition_kernel<<<GB, 256, 0, stream>>>(srcv, dstv, H, bstart, P, E);
    bucket_csr_kernel<<<NBUCK, 256, 0, stream>>>(P, bstart, rowoff, dis, csr_src, N);

    const int aggBlocks = (N * 16 + 255) / 256;  // 16 lanes per node
    const int gemmRows = (N + 63) / 64;          // 782

    // --- layer 1 ---
    gemm_mfma_kernel<128, false><<<dim3(gemmRows, 2), 256, 0, stream>>>(
        x, nullptr, nullptr, W1thi, W1tlo, dis, bufT, N);
    aggregate128_kernel<<<aggBlocks, 256, 0, stream>>>(
        rowoff, csr_src, dis, bufT, b1, bufHi, bufLo, N);

    // --- layer 2 ---
    gemm_mfma_kernel<128, true><<<dim3(gemmRows, 2), 256, 0, stream>>>(
        nullptr, bufHi, bufLo, Whthi, Whtlo, dis, bufT, N);
    aggregate128_kernel<<<aggBlocks, 256, 0, stream>>>(
        rowoff, csr_src, dis, bufT, bh, bufHi, bufLo, N);

    // --- layer 3 + head ---
    gemm_mfma_kernel<64, true><<<dim3(gemmRows, 1), 256, 0, stream>>>(
        nullptr, bufHi, bufLo, W2thi, W2tlo, dis, bufT, N);
    aggregate64_head_kernel<<<aggBlocks, 256, 0, stream>>>(
        rowoff, csr_src, dis, bufT, b2, Wout, bout, hout, out, N);
}